// Round 1
// baseline (173.361 us; speedup 1.0000x reference)
//
#include <hip/hip_runtime.h>

#define N_NODES 4096
#define IN_FEAT 256
#define N_HEADS 8
#define N_HIDDEN 64
#define OUT_FEAT (N_HEADS * N_HIDDEN)  // 512
#define NEG_SLOPE 0.2f

typedef _Float16 half8 __attribute__((ext_vector_type(8)));
typedef _Float16 h2 __attribute__((ext_vector_type(2)));
typedef float floatx4 __attribute__((ext_vector_type(4)));
typedef float floatx16 __attribute__((ext_vector_type(16)));
typedef float f4 __attribute__((ext_vector_type(4)));

// ---------------- fat producer: MFMA GEMM + epilogue | adj->bits ----------
// (validated R8-R12 kernel, unchanged)
__global__ __launch_bounds__(256) void produce(
    const float* __restrict__ H, const float* __restrict__ adj,
    const float* __restrict__ Wt, const float* __restrict__ a,
    _Float16* __restrict__ GT16, float* __restrict__ elT,
    _Float16* __restrict__ eR1h, _Float16* __restrict__ eR2h,
    unsigned long long* __restrict__ bits) {
  __shared__ _Float16 SM[4 * 64 * 64];  // 32 KB: Ah|Al|Bh|Bl
  const int t = threadIdx.x;
  const int bx = blockIdx.x, by = blockIdx.y;

  if (by >= 8) {
    const int c = bx * 8 + (by - 8);
    const size_t W0 = (size_t)c * 512;
    const int wv = t >> 6, lane = t & 63;
    for (int k0 = 0; k0 < 128; k0 += 8) {
      float v[8];
#pragma unroll
      for (int k = 0; k < 8; ++k)
        v[k] = adj[(W0 + wv * 128 + k0 + k) * 64 + lane];
#pragma unroll
      for (int k = 0; k < 8; ++k) {
        unsigned long long m = __ballot(v[k] != 0.f);
        if (lane == 0) bits[W0 + wv * 128 + k0 + k] = m;
      }
    }
    return;
  }

  _Float16* Ah = SM;
  _Float16* Al = SM + 4096;
  _Float16* Bh = SM + 8192;
  _Float16* Bl = SM + 12288;
  const int w = t >> 6, l = t & 63;
  const int n16 = l & 15, q = l >> 4;
  const int bi = bx, bo = by;
  const int m0 = bi * 64 + w * 16;

  floatx4 acc[4];
#pragma unroll
  for (int ct = 0; ct < 4; ++ct) acc[ct] = (floatx4)0.f;

  for (int kc = 0; kc < 4; ++kc) {
    if (kc) __syncthreads();
#pragma unroll
    for (int p = 0; p < 4; ++p) {
      const int idx = p * 256 + t;
      const int r = idx >> 4;
      const int c4 = (idx & 15) << 2;
      const int dst = r * 64 + ((((idx & 15) >> 1)) ^ (r & 7)) * 8 + (idx & 1) * 4;
      float4 hv = *(const float4*)(H + (size_t)(bi * 64 + r) * IN_FEAT + kc * 64 + c4);
      float4 wv = *(const float4*)(Wt + (size_t)(bo * 64 + r) * IN_FEAT + kc * 64 + c4);
      union { _Float16 h[4]; int2 d; } hh_, hl_, wh_, wl_;
      hh_.h[0] = (_Float16)hv.x; hh_.h[1] = (_Float16)hv.y;
      hh_.h[2] = (_Float16)hv.z; hh_.h[3] = (_Float16)hv.w;
      hl_.h[0] = (_Float16)(hv.x - (float)hh_.h[0]);
      hl_.h[1] = (_Float16)(hv.y - (float)hh_.h[1]);
      hl_.h[2] = (_Float16)(hv.z - (float)hh_.h[2]);
      hl_.h[3] = (_Float16)(hv.w - (float)hh_.h[3]);
      wh_.h[0] = (_Float16)wv.x; wh_.h[1] = (_Float16)wv.y;
      wh_.h[2] = (_Float16)wv.z; wh_.h[3] = (_Float16)wv.w;
      wl_.h[0] = (_Float16)(wv.x - (float)wh_.h[0]);
      wl_.h[1] = (_Float16)(wv.y - (float)wh_.h[1]);
      wl_.h[2] = (_Float16)(wv.z - (float)wh_.h[2]);
      wl_.h[3] = (_Float16)(wv.w - (float)wh_.h[3]);
      *(int2*)&Ah[dst] = hh_.d;
      *(int2*)&Al[dst] = hl_.d;
      *(int2*)&Bh[dst] = wh_.d;
      *(int2*)&Bl[dst] = wl_.d;
    }
    __syncthreads();
#pragma unroll
    for (int ks = 0; ks < 2; ++ks) {
      const int ao = (w * 16 + n16) * 64 + (((ks << 2) + q) ^ (n16 & 7)) * 8;
      half8 Afh = *(const half8*)&Ah[ao];
      half8 Afl = *(const half8*)&Al[ao];
#pragma unroll
      for (int ct = 0; ct < 4; ++ct) {
        const int bofs = (ct * 16 + n16) * 64 + (((ks << 2) + q) ^ (n16 & 7)) * 8;
        half8 Bfh = *(const half8*)&Bh[bofs];
        half8 Bfl = *(const half8*)&Bl[bofs];
        acc[ct] = __builtin_amdgcn_mfma_f32_16x16x32_f16(Afh, Bfh, acc[ct], 0, 0, 0);
        acc[ct] = __builtin_amdgcn_mfma_f32_16x16x32_f16(Afl, Bfh, acc[ct], 0, 0, 0);
        acc[ct] = __builtin_amdgcn_mfma_f32_16x16x32_f16(Afh, Bfl, acc[ct], 0, 0, 0);
      }
    }
  }

  float aLv[4], aRv[4];
#pragma unroll
  for (int ct = 0; ct < 4; ++ct) {
    aLv[ct] = a[ct * 16 + n16];
    aRv[ct] = a[64 + ct * 16 + n16];
  }
#pragma unroll
  for (int reg = 0; reg < 4; ++reg) {
    float sl = 0.f, sr = 0.f;
#pragma unroll
    for (int ct = 0; ct < 4; ++ct) {
      sl = fmaf(acc[ct][reg], aLv[ct], sl);
      sr = fmaf(acc[ct][reg], aRv[ct], sr);
    }
#pragma unroll
    for (int off = 1; off < 16; off <<= 1) {
      sl += __shfl_xor(sl, off);
      sr += __shfl_xor(sr, off);
    }
    if (n16 == 0) {
      const int rowi = m0 + q * 4 + reg;
      elT[(size_t)bo * N_NODES + rowi] = sl;
      eR1h[(size_t)bo * N_NODES + rowi] = (_Float16)__expf(sr);
      eR2h[(size_t)bo * N_NODES + rowi] = (_Float16)__expf(0.2f * sr);
    }
  }

  __syncthreads();
  _Float16* LG = SM;  // 64 x 72 halfs
#pragma unroll
  for (int ct = 0; ct < 4; ++ct)
#pragma unroll
    for (int reg = 0; reg < 4; ++reg)
      LG[(w * 16 + q * 4 + reg) * 72 + ct * 16 + n16] = (_Float16)acc[ct][reg];
  __syncthreads();
  {
    const int f = t >> 2, jq = t & 3;
    union { _Float16 hh[16]; int4 v[2]; } u;
#pragma unroll
    for (int k = 0; k < 16; ++k) u.hh[k] = LG[(jq * 16 + k) * 72 + f];
    _Float16* dst = GT16 + (size_t)(bo * 64 + f) * N_NODES + bi * 64 + jq * 16;
    *(int4*)dst = u.v[0];
    *(int4*)(dst + 8) = u.v[1];
  }
}

// ---------------- dense attention v9: 32x32x16 MFMA, j-quarter waves ------
// Block = 32 i-rows x 1 head x all 4096 j. 4 waves, wave w owns j-slice
// [w*1024, (w+1)*1024), 32 steps of 32 j. MFMA 32x32x16_f16: M=32 (all block
// rows), N=32 feats (2 ft tiles), K=16 j (2 chunks/step). Halves LDS B-reads
// per MAC vs v8's 16x16x32 and removes the rt duplication. eR read direct
// from global (register-prefetched, broadcast addresses) - no LDS staging.
// Gt LDS tile [64 feat][32 j] per wave, 16B slots XOR-swizzled ^(feat&3)
// applied on the gll SOURCE side (linear LDS dest, rule #21).
__global__ __launch_bounds__(256, 4) void attn_v9(
    const unsigned long long* __restrict__ bits, const _Float16* __restrict__ GT16,
    const float* __restrict__ elT, const _Float16* __restrict__ eR1h,
    const _Float16* __restrict__ eR2h, float* __restrict__ out) {
  __shared__ __align__(16) _Float16 Gt[2][4][2048];  // [par][wave][64f x 32j], 32 KB
  __shared__ float eL1s[32], eL2s[32];
  __shared__ float Zp[4][32];

  const int t = threadIdx.x;
  const int ib = blockIdx.x, h = blockIdx.y;
  const int i0 = ib * 32;
  const int w = t >> 6, l = t & 63;
  const int c31 = l & 31, hi = l >> 5, hi8 = hi * 8;

  // ---- gll source descriptors: call c stages bytes [c*1024, +1024) of the
  // wave tile; lane covers (feat = c*16 + l/4, slot p = l&3); source slot is
  // pre-swizzled p ^ (feat&3) so swizzled layout lands via linear LDS dest.
  const _Float16* gsrcs[4];
#pragma unroll
  for (int c = 0; c < 4; ++c) {
    const int feat = c * 16 + (l >> 2);
    const int p = l & 3;
    gsrcs[c] = GT16 + (size_t)(h * 64 + feat) * N_NODES + w * 1024 + (p ^ (feat & 3)) * 8;
  }

  const _Float16* er1p = eR1h + (size_t)h * N_NODES + w * 1024 + hi8;
  const _Float16* er2p = eR2h + (size_t)h * N_NODES + w * 1024 + hi8;
  const unsigned* bp = (const unsigned*)bits + (size_t)(i0 + c31) * 128 + w * 32;

  if (t < 32) {
    float e = elT[(size_t)h * N_NODES + i0 + t];
    eL1s[t] = __expf(e);
    eL2s[t] = __expf(0.2f * e);
  }

  // ---- stage step 0 into par=0; prefetch step-0 eR + bits into regs ----
#pragma unroll
  for (int c = 0; c < 4; ++c)
    __builtin_amdgcn_global_load_lds(
        (const __attribute__((address_space(1))) unsigned int*)gsrcs[c],
        (__attribute__((address_space(3))) unsigned int*)&Gt[0][w][c * 512],
        16, 0, 0);
  uint4 e1c0 = *(const uint4*)er1p;
  uint4 e1c1 = *(const uint4*)(er1p + 16);
  uint4 e2c0 = *(const uint4*)er2p;
  uint4 e2c1 = *(const uint4*)(er2p + 16);
  unsigned bvc = bp[0];
  __syncthreads();

  const _Float16 e1f = (_Float16)eL1s[c31];
  const _Float16 e2f = (_Float16)eL2s[c31];
  const h2 eL1h2 = {e1f, e1f};
  const h2 eL2h2 = {e2f, e2f};
  half8 Bones;
#pragma unroll
  for (int k = 0; k < 8; ++k) Bones[k] = (c31 == 0) ? (_Float16)1.f : (_Float16)0.f;

  // B-fragment LDS half-offsets (step-invariant): feat-major rows of 32 halfs,
  // logical slot s = ch*2+hi stored at s ^ (feat&3).
  int boff[2][2];
#pragma unroll
  for (int ft = 0; ft < 2; ++ft)
#pragma unroll
    for (int ch = 0; ch < 2; ++ch)
      boff[ft][ch] = (ft * 32 + c31) * 32 + (((ch * 2 + hi) ^ (c31 & 3)) * 8);

  floatx16 acc0 = (floatx16)0.f, acc1 = (floatx16)0.f, accZ = (floatx16)0.f;

  int par = 0;
  for (int step = 0; step < 32; ++step) {
    // ---- async-stage step+1 (Gt via gll; eR/bits via registers) ----
    uint4 e1n0 = e1c0, e1n1 = e1c1, e2n0 = e2c0, e2n1 = e2c1;
    unsigned bvn = bvc;
    if (step + 1 < 32) {
      const int np = par ^ 1;
#pragma unroll
      for (int c = 0; c < 4; ++c)
        __builtin_amdgcn_global_load_lds(
            (const __attribute__((address_space(1))) unsigned int*)(gsrcs[c] + (step + 1) * 32),
            (__attribute__((address_space(3))) unsigned int*)&Gt[np][w][c * 512],
            16, 0, 0);
      e1n0 = *(const uint4*)(er1p + (step + 1) * 32);
      e1n1 = *(const uint4*)(er1p + (step + 1) * 32 + 16);
      e2n0 = *(const uint4*)(er2p + (step + 1) * 32);
      e2n1 = *(const uint4*)(er2p + (step + 1) * 32 + 16);
      bvn = bp[step + 1];
    }
    // ---- compute current step: 2 K-chunks of 16 j ----
    const _Float16* gt = &Gt[par][w][0];
#pragma unroll
    for (int ch = 0; ch < 2; ++ch) {
      const unsigned byte = (bvc >> (ch * 16 + hi8)) & 0xffu;
      const uint4 r1 = ch ? e1c1 : e1c0;
      const uint4 r2 = ch ? e2c1 : e2c0;
      const unsigned r1a[4] = {r1.x, r1.y, r1.z, r1.w};
      const unsigned r2a[4] = {r2.x, r2.y, r2.z, r2.w};
      unsigned pr[4];
#pragma unroll
      for (int kk = 0; kk < 4; ++kk) {
        h2 pa = eL1h2 * __builtin_bit_cast(h2, r1a[kk]);
        h2 pb = eL2h2 * __builtin_bit_cast(h2, r2a[kk]);
        h2 pv = __builtin_elementwise_max(pa, pb);
        unsigned y = (byte >> (2 * kk)) & 3u;
        unsigned b01 = (y | (y << 15)) & 0x00010001u;
        unsigned keep = b01 * 0xffffu;
        pr[kk] = (__builtin_bit_cast(unsigned, pv) & keep) | (0x3C003C00u & ~keep);
      }
      const uint4 prv = {pr[0], pr[1], pr[2], pr[3]};
      half8 Af = __builtin_bit_cast(half8, prv);
      half8 B0 = *(const half8*)&gt[boff[0][ch]];
      half8 B1 = *(const half8*)&gt[boff[1][ch]];
      acc0 = __builtin_amdgcn_mfma_f32_32x32x16_f16(Af, B0, acc0, 0, 0, 0);
      acc1 = __builtin_amdgcn_mfma_f32_32x32x16_f16(Af, B1, acc1, 0, 0, 0);
      accZ = __builtin_amdgcn_mfma_f32_32x32x16_f16(Af, Bones, accZ, 0, 0, 0);
    }
    e1c0 = e1n0; e1c1 = e1n1; e2c0 = e2n0; e2c1 = e2n1; bvc = bvn;
    __syncthreads();
    par ^= 1;
  }

  // ---- combine 4 j-quarter partials, normalize, store ----
  // fp32 scratch reuses Gt (32 KB = 4 x [32 rows][64 cols]); columns rotated
  // by row*4 to break the stride-64 bank alias on the float4 re-reads.
  float* sc = (float*)&Gt[0][0][0];
#pragma unroll
  for (int ft = 0; ft < 2; ++ft) {
#pragma unroll
    for (int r = 0; r < 16; ++r) {
      const int row = (r & 3) + 8 * (r >> 2) + 4 * hi;
      const int col = (ft * 32 + c31 + row * 4) & 63;
      sc[w * 2048 + row * 64 + col] = ft ? acc1[r] : acc0[r];
    }
  }
  if (c31 == 0) {
#pragma unroll
    for (int r = 0; r < 16; ++r)
      Zp[w][(r & 3) + 8 * (r >> 2) + 4 * hi] = accZ[r];
  }
  __syncthreads();
  {
    const int row = t >> 3, cg = (t & 7) * 8;
    const int sA = (cg + row * 4) & 63;
    const int sB = (cg + 4 + row * 4) & 63;
    f4 s0 = (f4)0.f, s1 = (f4)0.f;
#pragma unroll
    for (int w4 = 0; w4 < 4; ++w4) {
      s0 += *(const f4*)&sc[w4 * 2048 + row * 64 + sA];
      s1 += *(const f4*)&sc[w4 * 2048 + row * 64 + sB];
    }
    const float Z = Zp[0][row] + Zp[1][row] + Zp[2][row] + Zp[3][row];
    const float invz = 1.f / Z;
    s0 *= invz;
    s1 *= invz;
    float* op = out + (size_t)(i0 + row) * OUT_FEAT + h * 64 + cg;
    *(f4*)op = s0;
    *(f4*)(op + 4) = s1;
  }
}

extern "C" void kernel_launch(void* const* d_in, const int* in_sizes, int n_in,
                              void* d_out, int out_size, void* d_ws, size_t ws_size,
                              hipStream_t stream) {
  const float* h   = (const float*)d_in[0];
  const float* adj = (const float*)d_in[1];
  const float* W   = (const float*)d_in[2];
  const float* a   = (const float*)d_in[3];
  float* out = (float*)d_out;

  char* ws = (char*)d_ws;
  _Float16* GT16 = (_Float16*)ws;                                         // 4 MB
  unsigned long long* bits = (unsigned long long*)(ws + 4u * 1024 * 1024);// 2 MB
  float* elT = (float*)(ws + 6u * 1024 * 1024);                           // 128 KB
  _Float16* eR1h = (_Float16*)(ws + 6u * 1024 * 1024 + 128 * 1024);       // 64 KB
  _Float16* eR2h = (_Float16*)(ws + 6u * 1024 * 1024 + 192 * 1024);       // 64 KB

  produce<<<dim3(64, 16), 256, 0, stream>>>(h, adj, W, a, GT16, elT, eR1h, eR2h, bits);
  attn_v9<<<dim3(128, 8), 256, 0, stream>>>(bits, GT16, elT, eR1h, eR2h, out);
}

// Round 2
// 171.022 us; speedup vs baseline: 1.0137x; 1.0137x over previous
//
#include <hip/hip_runtime.h>

#define N_NODES 4096
#define IN_FEAT 256
#define N_HEADS 8
#define N_HIDDEN 64
#define OUT_FEAT (N_HEADS * N_HIDDEN)  // 512
#define NEG_SLOPE 0.2f

typedef _Float16 half8 __attribute__((ext_vector_type(8)));
typedef _Float16 h2 __attribute__((ext_vector_type(2)));
typedef float floatx4 __attribute__((ext_vector_type(4)));
typedef float floatx16 __attribute__((ext_vector_type(16)));
typedef float f4 __attribute__((ext_vector_type(4)));

// ---------------- fat producer: MFMA GEMM + epilogue | adj->bits ----------
// (validated R8-R12 kernel, unchanged)
__global__ __launch_bounds__(256) void produce(
    const float* __restrict__ H, const float* __restrict__ adj,
    const float* __restrict__ Wt, const float* __restrict__ a,
    _Float16* __restrict__ GT16, float* __restrict__ elT,
    _Float16* __restrict__ eR1h, _Float16* __restrict__ eR2h,
    unsigned long long* __restrict__ bits) {
  __shared__ _Float16 SM[4 * 64 * 64];  // 32 KB: Ah|Al|Bh|Bl
  const int t = threadIdx.x;
  const int bx = blockIdx.x, by = blockIdx.y;

  if (by >= 8) {
    const int c = bx * 8 + (by - 8);
    const size_t W0 = (size_t)c * 512;
    const int wv = t >> 6, lane = t & 63;
    for (int k0 = 0; k0 < 128; k0 += 8) {
      float v[8];
#pragma unroll
      for (int k = 0; k < 8; ++k)
        v[k] = adj[(W0 + wv * 128 + k0 + k) * 64 + lane];
#pragma unroll
      for (int k = 0; k < 8; ++k) {
        unsigned long long m = __ballot(v[k] != 0.f);
        if (lane == 0) bits[W0 + wv * 128 + k0 + k] = m;
      }
    }
    return;
  }

  _Float16* Ah = SM;
  _Float16* Al = SM + 4096;
  _Float16* Bh = SM + 8192;
  _Float16* Bl = SM + 12288;
  const int w = t >> 6, l = t & 63;
  const int n16 = l & 15, q = l >> 4;
  const int bi = bx, bo = by;
  const int m0 = bi * 64 + w * 16;

  floatx4 acc[4];
#pragma unroll
  for (int ct = 0; ct < 4; ++ct) acc[ct] = (floatx4)0.f;

  for (int kc = 0; kc < 4; ++kc) {
    if (kc) __syncthreads();
#pragma unroll
    for (int p = 0; p < 4; ++p) {
      const int idx = p * 256 + t;
      const int r = idx >> 4;
      const int c4 = (idx & 15) << 2;
      const int dst = r * 64 + ((((idx & 15) >> 1)) ^ (r & 7)) * 8 + (idx & 1) * 4;
      float4 hv = *(const float4*)(H + (size_t)(bi * 64 + r) * IN_FEAT + kc * 64 + c4);
      float4 wv = *(const float4*)(Wt + (size_t)(bo * 64 + r) * IN_FEAT + kc * 64 + c4);
      union { _Float16 h[4]; int2 d; } hh_, hl_, wh_, wl_;
      hh_.h[0] = (_Float16)hv.x; hh_.h[1] = (_Float16)hv.y;
      hh_.h[2] = (_Float16)hv.z; hh_.h[3] = (_Float16)hv.w;
      hl_.h[0] = (_Float16)(hv.x - (float)hh_.h[0]);
      hl_.h[1] = (_Float16)(hv.y - (float)hh_.h[1]);
      hl_.h[2] = (_Float16)(hv.z - (float)hh_.h[2]);
      hl_.h[3] = (_Float16)(hv.w - (float)hh_.h[3]);
      wh_.h[0] = (_Float16)wv.x; wh_.h[1] = (_Float16)wv.y;
      wh_.h[2] = (_Float16)wv.z; wh_.h[3] = (_Float16)wv.w;
      wl_.h[0] = (_Float16)(wv.x - (float)wh_.h[0]);
      wl_.h[1] = (_Float16)(wv.y - (float)wh_.h[1]);
      wl_.h[2] = (_Float16)(wv.z - (float)wh_.h[2]);
      wl_.h[3] = (_Float16)(wv.w - (float)wh_.h[3]);
      *(int2*)&Ah[dst] = hh_.d;
      *(int2*)&Al[dst] = hl_.d;
      *(int2*)&Bh[dst] = wh_.d;
      *(int2*)&Bl[dst] = wl_.d;
    }
    __syncthreads();
#pragma unroll
    for (int ks = 0; ks < 2; ++ks) {
      const int ao = (w * 16 + n16) * 64 + (((ks << 2) + q) ^ (n16 & 7)) * 8;
      half8 Afh = *(const half8*)&Ah[ao];
      half8 Afl = *(const half8*)&Al[ao];
#pragma unroll
      for (int ct = 0; ct < 4; ++ct) {
        const int bofs = (ct * 16 + n16) * 64 + (((ks << 2) + q) ^ (n16 & 7)) * 8;
        half8 Bfh = *(const half8*)&Bh[bofs];
        half8 Bfl = *(const half8*)&Bl[bofs];
        acc[ct] = __builtin_amdgcn_mfma_f32_16x16x32_f16(Afh, Bfh, acc[ct], 0, 0, 0);
        acc[ct] = __builtin_amdgcn_mfma_f32_16x16x32_f16(Afl, Bfh, acc[ct], 0, 0, 0);
        acc[ct] = __builtin_amdgcn_mfma_f32_16x16x32_f16(Afh, Bfl, acc[ct], 0, 0, 0);
      }
    }
  }

  float aLv[4], aRv[4];
#pragma unroll
  for (int ct = 0; ct < 4; ++ct) {
    aLv[ct] = a[ct * 16 + n16];
    aRv[ct] = a[64 + ct * 16 + n16];
  }
#pragma unroll
  for (int reg = 0; reg < 4; ++reg) {
    float sl = 0.f, sr = 0.f;
#pragma unroll
    for (int ct = 0; ct < 4; ++ct) {
      sl = fmaf(acc[ct][reg], aLv[ct], sl);
      sr = fmaf(acc[ct][reg], aRv[ct], sr);
    }
#pragma unroll
    for (int off = 1; off < 16; off <<= 1) {
      sl += __shfl_xor(sl, off);
      sr += __shfl_xor(sr, off);
    }
    if (n16 == 0) {
      const int rowi = m0 + q * 4 + reg;
      elT[(size_t)bo * N_NODES + rowi] = sl;
      eR1h[(size_t)bo * N_NODES + rowi] = (_Float16)__expf(sr);
      eR2h[(size_t)bo * N_NODES + rowi] = (_Float16)__expf(0.2f * sr);
    }
  }

  __syncthreads();
  _Float16* LG = SM;  // 64 x 72 halfs
#pragma unroll
  for (int ct = 0; ct < 4; ++ct)
#pragma unroll
    for (int reg = 0; reg < 4; ++reg)
      LG[(w * 16 + q * 4 + reg) * 72 + ct * 16 + n16] = (_Float16)acc[ct][reg];
  __syncthreads();
  {
    const int f = t >> 2, jq = t & 3;
    union { _Float16 hh[16]; int4 v[2]; } u;
#pragma unroll
    for (int k = 0; k < 16; ++k) u.hh[k] = LG[(jq * 16 + k) * 72 + f];
    _Float16* dst = GT16 + (size_t)(bo * 64 + f) * N_NODES + bi * 64 + jq * 16;
    *(int4*)dst = u.v[0];
    *(int4*)(dst + 8) = u.v[1];
  }
}

// ---------------- dense attention v10: 32x32x16 MFMA, barrier-free loop ---
// v9 structure (j-quarter waves, M=32 covers all block rows) with two fixes:
// 1. Correct bank-group swizzle. Byte addr = feat*64 + slot*16; group bits
//    [6:4] = slot | ((feat&1)<<2). Per-row permutation phys = logical ^
//    ((feat>>1)&3) makes each 16-lane quarter hit all 8 groups 2x (free).
//    v9's ^(c31&3) hit only 4 groups 4x -> 6.4M conflicts, the regression.
// 2. No per-step __syncthreads. Waves share NO LDS in the main loop (each
//    stages+reads its own Gt tile), so the barrier's vmcnt(0) drain was pure
//    serialization of staging completion. Replaced by per-wave counted
//    s_waitcnt vmcnt(9): exactly 9 vmem ops issue per iteration (4 gll +
//    4 eR dwordx4 + 1 bits), wraparound-issued on the last step so the
//    count is uniform. Prev iteration's glls are thus complete before the
//    ds_reads; this iteration's stay in flight under compute (T4).
// One __syncthreads after the loop: epilogue scratch reuses Gt across waves.
__global__ __launch_bounds__(256, 4) void attn_v10(
    const unsigned long long* __restrict__ bits, const _Float16* __restrict__ GT16,
    const float* __restrict__ elT, const _Float16* __restrict__ eR1h,
    const _Float16* __restrict__ eR2h, float* __restrict__ out) {
  __shared__ __align__(16) _Float16 Gt[2][4][2048];  // [par][wave][64f x 32j], 32 KB
  __shared__ float eL1s[32], eL2s[32];
  __shared__ float Zp[4][32];

  const int t = threadIdx.x;
  const int ib = blockIdx.x, h = blockIdx.y;
  const int i0 = ib * 32;
  const int w = t >> 6, l = t & 63;
  const int c31 = l & 31, hi = l >> 5, hi8 = hi * 8;

  // gll source descriptors: call c stages bytes [c*1024,+1024) of the wave
  // tile; lane covers (feat = c*16 + l/4, phys slot p = l&3). Source chunk is
  // pre-swizzled p ^ ((feat>>1)&3) so the swizzled layout lands via the
  // linear LDS dest (rule #21).
  const _Float16* gsrcs[4];
#pragma unroll
  for (int c = 0; c < 4; ++c) {
    const int feat = c * 16 + (l >> 2);
    const int p = l & 3;
    gsrcs[c] = GT16 + (size_t)(h * 64 + feat) * N_NODES + w * 1024 +
               (p ^ ((feat >> 1) & 3)) * 8;
  }

  const _Float16* er1p = eR1h + (size_t)h * N_NODES + w * 1024 + hi8;
  const _Float16* er2p = eR2h + (size_t)h * N_NODES + w * 1024 + hi8;
  const unsigned* bp = (const unsigned*)bits + (size_t)(i0 + c31) * 128 + w * 32;

  if (t < 32) {
    float e = elT[(size_t)h * N_NODES + i0 + t];
    eL1s[t] = __expf(e);
    eL2s[t] = __expf(0.2f * e);
  }

  // ---- prologue: stage step 0 into par=0; prefetch step-0 eR + bits ----
#pragma unroll
  for (int c = 0; c < 4; ++c)
    __builtin_amdgcn_global_load_lds(
        (const __attribute__((address_space(1))) unsigned int*)gsrcs[c],
        (__attribute__((address_space(3))) unsigned int*)&Gt[0][w][c * 512],
        16, 0, 0);
  uint4 e1c0 = *(const uint4*)er1p;
  uint4 e1c1 = *(const uint4*)(er1p + 16);
  uint4 e2c0 = *(const uint4*)er2p;
  uint4 e2c1 = *(const uint4*)(er2p + 16);
  unsigned bvc = bp[0];
  __syncthreads();  // eL1s visibility; also drains prologue staging

  const _Float16 e1f = (_Float16)eL1s[c31];
  const _Float16 e2f = (_Float16)eL2s[c31];
  const h2 eL1h2 = {e1f, e1f};
  const h2 eL2h2 = {e2f, e2f};
  half8 Bones;
#pragma unroll
  for (int k = 0; k < 8; ++k) Bones[k] = (c31 == 0) ? (_Float16)1.f : (_Float16)0.f;

  // B-fragment LDS half-offsets (step-invariant): feat-major rows of 32
  // halfs; logical slot s = ch*2+hi stored at s ^ ((feat>>1)&3), and for
  // feat = ft*32 + c31 the XOR term is (c31>>1)&3.
  int boff[2][2];
#pragma unroll
  for (int ft = 0; ft < 2; ++ft)
#pragma unroll
    for (int ch = 0; ch < 2; ++ch)
      boff[ft][ch] = (ft * 32 + c31) * 32 + (((ch * 2 + hi) ^ ((c31 >> 1) & 3)) * 8);

  floatx16 acc0 = (floatx16)0.f, acc1 = (floatx16)0.f, accZ = (floatx16)0.f;

  int par = 0;
  for (int step = 0; step < 32; ++step) {
    // ---- issue stage for step+1 (wraparound on last step keeps the vmem
    // count at exactly 9/iter; wrapped data is staged but never read) ----
    const int nxt = (step + 1) & 31;
    const int np = par ^ 1;
#pragma unroll
    for (int c = 0; c < 4; ++c)
      __builtin_amdgcn_global_load_lds(
          (const __attribute__((address_space(1))) unsigned int*)(gsrcs[c] + nxt * 32),
          (__attribute__((address_space(3))) unsigned int*)&Gt[np][w][c * 512],
          16, 0, 0);
    uint4 e1n0 = *(const uint4*)(er1p + nxt * 32);
    uint4 e1n1 = *(const uint4*)(er1p + nxt * 32 + 16);
    uint4 e2n0 = *(const uint4*)(er2p + nxt * 32);
    uint4 e2n1 = *(const uint4*)(er2p + nxt * 32 + 16);
    unsigned bvn = bp[nxt];

    // ---- per-wave wait: everything older than this iter's 9 ops is done,
    // i.e. the glls that filled Gt[par]. No cross-wave barrier needed. ----
    asm volatile("s_waitcnt vmcnt(9)" ::: "memory");
    __builtin_amdgcn_sched_barrier(0);

    // ---- compute current step: 2 K-chunks of 16 j ----
    const _Float16* gt = &Gt[par][w][0];
#pragma unroll
    for (int ch = 0; ch < 2; ++ch) {
      const unsigned byte = (bvc >> (ch * 16 + hi8)) & 0xffu;
      const uint4 r1 = ch ? e1c1 : e1c0;
      const uint4 r2 = ch ? e2c1 : e2c0;
      const unsigned r1a[4] = {r1.x, r1.y, r1.z, r1.w};
      const unsigned r2a[4] = {r2.x, r2.y, r2.z, r2.w};
      unsigned pr[4];
#pragma unroll
      for (int kk = 0; kk < 4; ++kk) {
        h2 pa = eL1h2 * __builtin_bit_cast(h2, r1a[kk]);
        h2 pb = eL2h2 * __builtin_bit_cast(h2, r2a[kk]);
        h2 pv = __builtin_elementwise_max(pa, pb);
        unsigned y = (byte >> (2 * kk)) & 3u;
        unsigned b01 = (y | (y << 15)) & 0x00010001u;
        unsigned keep = b01 * 0xffffu;
        pr[kk] = (__builtin_bit_cast(unsigned, pv) & keep) | (0x3C003C00u & ~keep);
      }
      const uint4 prv = {pr[0], pr[1], pr[2], pr[3]};
      half8 Af = __builtin_bit_cast(half8, prv);
      half8 B0 = *(const half8*)&gt[boff[0][ch]];
      half8 B1 = *(const half8*)&gt[boff[1][ch]];
      acc0 = __builtin_amdgcn_mfma_f32_32x32x16_f16(Af, B0, acc0, 0, 0, 0);
      acc1 = __builtin_amdgcn_mfma_f32_32x32x16_f16(Af, B1, acc1, 0, 0, 0);
      accZ = __builtin_amdgcn_mfma_f32_32x32x16_f16(Af, Bones, accZ, 0, 0, 0);
    }
    e1c0 = e1n0; e1c1 = e1n1; e2c0 = e2n0; e2c1 = e2n1; bvc = bvn;
    par ^= 1;
  }

  // ---- epilogue: scratch reuses Gt across waves -> must sync first ----
  __syncthreads();

  // combine 4 j-quarter partials, normalize, store. fp32 scratch = 4 x
  // [32 rows][64 cols]; columns rotated by row*4 to break the stride-64
  // bank alias on the float4 re-reads.
  float* sc = (float*)&Gt[0][0][0];
#pragma unroll
  for (int ft = 0; ft < 2; ++ft) {
#pragma unroll
    for (int r = 0; r < 16; ++r) {
      const int row = (r & 3) + 8 * (r >> 2) + 4 * hi;
      const int col = (ft * 32 + c31 + row * 4) & 63;
      sc[w * 2048 + row * 64 + col] = ft ? acc1[r] : acc0[r];
    }
  }
  if (c31 == 0) {
#pragma unroll
    for (int r = 0; r < 16; ++r)
      Zp[w][(r & 3) + 8 * (r >> 2) + 4 * hi] = accZ[r];
  }
  __syncthreads();
  {
    const int row = t >> 3, cg = (t & 7) * 8;
    const int sA = (cg + row * 4) & 63;
    const int sB = (cg + 4 + row * 4) & 63;
    f4 s0 = (f4)0.f, s1 = (f4)0.f;
#pragma unroll
    for (int w4 = 0; w4 < 4; ++w4) {
      s0 += *(const f4*)&sc[w4 * 2048 + row * 64 + sA];
      s1 += *(const f4*)&sc[w4 * 2048 + row * 64 + sB];
    }
    const float Z = Zp[0][row] + Zp[1][row] + Zp[2][row] + Zp[3][row];
    const float invz = 1.f / Z;
    s0 *= invz;
    s1 *= invz;
    float* op = out + (size_t)(i0 + row) * OUT_FEAT + h * 64 + cg;
    *(f4*)op = s0;
    *(f4*)(op + 4) = s1;
  }
}

extern "C" void kernel_launch(void* const* d_in, const int* in_sizes, int n_in,
                              void* d_out, int out_size, void* d_ws, size_t ws_size,
                              hipStream_t stream) {
  const float* h   = (const float*)d_in[0];
  const float* adj = (const float*)d_in[1];
  const float* W   = (const float*)d_in[2];
  const float* a   = (const float*)d_in[3];
  float* out = (float*)d_out;

  char* ws = (char*)d_ws;
  _Float16* GT16 = (_Float16*)ws;                                         // 4 MB
  unsigned long long* bits = (unsigned long long*)(ws + 4u * 1024 * 1024);// 2 MB
  float* elT = (float*)(ws + 6u * 1024 * 1024);                           // 128 KB
  _Float16* eR1h = (_Float16*)(ws + 6u * 1024 * 1024 + 128 * 1024);       // 64 KB
  _Float16* eR2h = (_Float16*)(ws + 6u * 1024 * 1024 + 192 * 1024);       // 64 KB

  produce<<<dim3(64, 16), 256, 0, stream>>>(h, adj, W, a, GT16, elT, eR1h, eR2h, bits);
  attn_v10<<<dim3(128, 8), 256, 0, stream>>>(bits, GT16, elT, eR1h, eR2h, out);
}